// Round 4
// baseline (527.068 us; speedup 1.0000x reference)
//
#include <hip/hip_runtime.h>
#include <hip/hip_bf16.h>
#include <math.h>

#define N_PROTS 2048
#define N_MOLS  16384
#define DIM     768
#define SHIFT   16.0f
#define MARGIN  0.5f

typedef __attribute__((ext_vector_type(8))) short short8;
typedef __attribute__((ext_vector_type(4))) float f32x4;
typedef __attribute__((ext_vector_type(4))) unsigned short us4;
typedef __attribute__((ext_vector_type(8))) unsigned short us8;

__device__ __forceinline__ unsigned short bf16rnd(float x) {
    unsigned int u = __float_as_uint(x);
    u += 0x7fffu + ((u >> 16) & 1u);   // round-to-nearest-even
    return (unsigned short)(u >> 16);
}

__device__ __forceinline__ void gload16(const void* g, void* l) {
    __builtin_amdgcn_global_load_lds(
        (const __attribute__((address_space(1))) unsigned int*)g,
        (__attribute__((address_space(3))) unsigned int*)l, 16, 0, 0);
}

__device__ __forceinline__ int sig4(int x) { return (x + (x >> 2)) & 3; }

__device__ __forceinline__ float aload(const float* p) {
    return __hip_atomic_load(p, __ATOMIC_RELAXED, __HIP_MEMORY_SCOPE_AGENT);
}

// ws layout:
//  floats [0, 34824): 0..2048 row_sumexp | 2048..18432 col_sumexp |
//                     18432..34816 pos_sim | 34816..34824 scalars
//  scalars: [0]=relu-sum  [5]=grid barrier ctr (u32)  [6]=finalize ticket (u32)
//  then 16B-aligned: protBf (2048*768 bf16), molBf (16384*768 bf16)
#define ACC_FLOATS 34824
#define PROT_BF_OFF_B 139296ull                      // 34824*4, 16B aligned
#define PROT_BF_BYTES (2048ull*768*2)
#define MOL_BF_OFF_B  (PROT_BF_OFF_B + PROT_BF_BYTES)
#define MOL_BF_BYTES  (16384ull*768*2)
#define WS_NEED       (MOL_BF_OFF_B + MOL_BF_BYTES)  // ~28.5 MB

#define GROUPS  ((size_t)(N_PROTS + N_MOLS) * DIM / 8)   // 1,769,472 16B chunks
#define PROT_G  ((size_t)N_PROTS * DIM / 8)              // 196,608

// =====================================================================
// fused_all: ONE kernel = convert + grid-barrier + GEMM(2 C-tiles) + finalize.
// Grid 256 x 512; 128 KB LDS -> exactly 1 block/CU -> all 256 co-resident,
// so the atomic grid barrier cannot deadlock (bounded spin regardless).
// Purpose of this round: every µs of GPU work is now inside ONE dispatch,
// so total - dur(fused_all) measures the harness/launch overhead exactly.
// =====================================================================
__global__ __launch_bounds__(512)
void fused_all(const float* __restrict__ prot, const float* __restrict__ mol,
               const float* __restrict__ pic50, const float* __restrict__ scale_p,
               unsigned short* __restrict__ protBf, unsigned short* __restrict__ molBf,
               float* __restrict__ wsBase, float* __restrict__ out)
{
    __shared__ unsigned short As[4][256][32];   // 64 KB
    __shared__ unsigned short Bs[4][256][32];   // 64 KB
    __shared__ float redBuf[8];
    __shared__ float rbuf2[8][4];
    __shared__ unsigned int winnerFlag;

    float* row_se  = wsBase;
    float* col_se  = wsBase + 2048;
    float* pos_sim = wsBase + 2048 + 16384;
    float* scalars = wsBase + 34816;
    unsigned int* bar  = (unsigned int*)(scalars + 5);
    unsigned int* tick = (unsigned int*)(scalars + 6);

    const int tid = threadIdx.x;
    const int bid = blockIdx.x;                // 0..255
    const size_t lin = (size_t)bid * 512 + tid;

    // ---------------- phase A: convert fp32->bf16 + zero accumulators ------
    if (lin < 8704) {                          // floats [0, 34816) = 8704 f4
        float4 z = {0.f, 0.f, 0.f, 0.f};
        ((float4*)wsBase)[lin] = z;
    }
    for (size_t g = lin; g < GROUPS; g += (size_t)256 * 512) {
        const float* src;
        unsigned short* dst;
        if (g < PROT_G) { src = prot + g * 8; dst = protBf + g * 8; }
        else            { size_t u = g - PROT_G; src = mol + u * 8; dst = molBf + u * 8; }
        float4 v0 = ((const float4*)src)[0];
        float4 v1 = ((const float4*)src)[1];
        us8 o;
        o[0] = bf16rnd(v0.x); o[1] = bf16rnd(v0.y); o[2] = bf16rnd(v0.z); o[3] = bf16rnd(v0.w);
        o[4] = bf16rnd(v1.x); o[5] = bf16rnd(v1.y); o[6] = bf16rnd(v1.z); o[7] = bf16rnd(v1.w);
        *(us8*)dst = o;
    }

    // ---------------- grid barrier (all 256 blocks co-resident) ------------
    __threadfence();            // flush this thread's stores device-wide
    __syncthreads();            // all waves of the block flushed
    if (tid == 0) {
        __hip_atomic_fetch_add(bar, 1u, __ATOMIC_ACQ_REL, __HIP_MEMORY_SCOPE_AGENT);
        unsigned int spins = 0;
        while (__hip_atomic_load(bar, __ATOMIC_ACQUIRE, __HIP_MEMORY_SCOPE_AGENT) < 256u) {
            __builtin_amdgcn_s_sleep(1);
            if (++spins > 200000000u) break;   // fail loud (wrong result), not hang
        }
    }
    __syncthreads();

    // ---------------- phase B: GEMM, two 256x256 C-tiles ------------------
    const int xcd = bid & 7;
    const int s   = bid >> 3;                  // 0..31
    const int by  = s >> 2;                    // 0..7
    const int bxh = xcd * 4 + (s & 3);         // 0..31 -> bx = 2*bxh + ct

    const int wave = tid >> 6;
    const int lane = tid & 63;
    const int wm = wave >> 2;                  // 0..1
    const int wn = wave & 3;                   // 0..3
    const int l15 = lane & 15;
    const int q   = lane >> 4;

    const int rsub = lane >> 2;                // 0..15
    const int cs   = lane & 3;
    const int csrc = (cs ^ sig4(rsub)) << 3;

    const int fArow = wm * 128 + l15;
    const int fBrow = wn * 64 + l15;
    const int fsw   = (q ^ sig4(l15)) << 3;

    const float scale = scale_p[0];
    const int rowBase = by * 256;
    float rl = 0.f;

#define STAGE_A(sl, ptr) do { \
    gload16((ptr),                     &As[sl][wave * 32][0]);      \
    gload16((ptr) + (size_t)16 * DIM,  &As[sl][wave * 32 + 16][0]); \
} while (0)
#define STAGE_B(sl, ptr) do { \
    gload16((ptr),                     &Bs[sl][wave * 32][0]);      \
    gload16((ptr) + (size_t)16 * DIM,  &Bs[sl][wave * 32 + 16][0]); \
} while (0)

#pragma unroll 1
    for (int ct = 0; ct < 2; ++ct) {
        const int colBase = (2 * bxh + ct) * 256;
        const unsigned short* aP =
            protBf + (size_t)(rowBase + wave * 32 + rsub) * DIM + csrc;
        const unsigned short* bP =
            molBf  + (size_t)(colBase + wave * 32 + rsub) * DIM + csrc;

        f32x4 acc[8][4];
#pragma unroll
        for (int i = 0; i < 8; ++i)
#pragma unroll
            for (int j = 0; j < 4; ++j) acc[i][j] = (f32x4){0.f, 0.f, 0.f, 0.f};

        STAGE_A(0, aP);      STAGE_B(0, bP);
        STAGE_A(1, aP + 32); STAGE_B(1, bP + 32);
        STAGE_A(2, aP + 64); STAGE_B(2, bP + 64);

#pragma unroll 1
        for (int t = 0; t < 24; ++t) {
            const int sl = t & 3;
            const int pf = (t + 3) & 3;
            const int kt = (t < 21) ? (t + 3) : (t - 5);   // tail: dummy re-stage
            const unsigned short* aPt = aP + (size_t)kt * 32;
            const unsigned short* bPt = bP + (size_t)kt * 32;

            asm volatile("s_waitcnt vmcnt(8)" ::: "memory");
            __builtin_amdgcn_s_barrier();
            __builtin_amdgcn_sched_barrier(0);

            short8 aF[4], bF[4];
#pragma unroll
            for (int ni = 0; ni < 4; ++ni)
                bF[ni] = *(const short8*)&Bs[sl][fBrow + ni * 16][fsw];
#pragma unroll
            for (int mi = 0; mi < 4; ++mi)
                aF[mi] = *(const short8*)&As[sl][fArow + mi * 16][fsw];
            STAGE_A(pf, aPt);
            __builtin_amdgcn_s_setprio(1);
#pragma unroll
            for (int mi = 0; mi < 4; ++mi)
#pragma unroll
                for (int ni = 0; ni < 4; ++ni)
                    acc[mi][ni] = __builtin_amdgcn_mfma_f32_16x16x32_bf16(
                        aF[mi], bF[ni], acc[mi][ni], 0, 0, 0);
            __builtin_amdgcn_s_setprio(0);

#pragma unroll
            for (int mi = 0; mi < 4; ++mi)
                aF[mi] = *(const short8*)&As[sl][fArow + 64 + mi * 16][fsw];
            STAGE_B(pf, bPt);
            __builtin_amdgcn_s_setprio(1);
#pragma unroll
            for (int mi = 0; mi < 4; ++mi)
#pragma unroll
                for (int ni = 0; ni < 4; ++ni)
                    acc[4 + mi][ni] = __builtin_amdgcn_mfma_f32_16x16x32_bf16(
                        aF[mi], bF[ni], acc[4 + mi][ni], 0, 0, 0);
            __builtin_amdgcn_s_setprio(0);
        }
        asm volatile("s_waitcnt vmcnt(0)" ::: "memory");   // retire dummy stages

        // ---- epilogue for this C-tile ----
        float csum[4] = {0.f, 0.f, 0.f, 0.f};
#pragma unroll
        for (int mi = 0; mi < 8; ++mi) {
            float rs[4] = {0.f, 0.f, 0.f, 0.f};
#pragma unroll
            for (int ni = 0; ni < 4; ++ni) {
#pragma unroll
                for (int r = 0; r < 4; ++r) {
                    float sim = acc[mi][ni][r] * scale;
                    float e = __expf(sim - SHIFT);
                    rs[r] += e;
                    csum[ni] += e;
                    rl += fmaxf(sim, 0.f);
                    int rg = rowBase + wm * 128 + mi * 16 + q * 4 + r;
                    int cg = colBase + wn * 64 + ni * 16 + l15;
                    if ((cg >> 3) == rg) pos_sim[cg] = sim;   // unique writer
                }
            }
#pragma unroll
            for (int r = 0; r < 4; ++r) {
                float v = rs[r];
                v += __shfl_xor(v, 1); v += __shfl_xor(v, 2);
                v += __shfl_xor(v, 4); v += __shfl_xor(v, 8);
                if (l15 == 0)
                    atomicAdd(&row_se[rowBase + wm * 128 + mi * 16 + q * 4 + r], v);
            }
        }
#pragma unroll
        for (int ni = 0; ni < 4; ++ni) {
            float v = csum[ni];
            v += __shfl_xor(v, 16); v += __shfl_xor(v, 32);
            if (q == 0)
                atomicAdd(&col_se[colBase + wn * 64 + ni * 16 + l15], v);
        }
        __syncthreads();   // all waves done with As/Bs before next ct restages
    }
#undef STAGE_A
#undef STAGE_B

    // block-local relu-sum -> one atomic
#pragma unroll
    for (int m = 1; m < 64; m <<= 1) rl += __shfl_xor(rl, m);
    if (lane == 0) redBuf[wave] = rl;
    __syncthreads();
    if (tid == 0) {
        float sv = 0.f;
#pragma unroll
        for (int w = 0; w < 8; ++w) sv += redBuf[w];
        atomicAdd(&scalars[0], sv);
    }

    // ---------------- phase C: ticket; last block finalizes ----------------
    __threadfence();
    __syncthreads();
    if (tid == 0) {
        unsigned int old = __hip_atomic_fetch_add(tick, 1u, __ATOMIC_ACQ_REL,
                                                  __HIP_MEMORY_SCOPE_AGENT);
        winnerFlag = (old == 255u) ? 1u : 0u;
    }
    __syncthreads();
    if (!winnerFlag) return;

    // winner block: full finalize with 512 threads; agent-scope loads for
    // cross-XCD visibility of other blocks' stores/atomics.
    float m2p = 0.f, p2m = 0.f, rank = 0.f, prelu = 0.f;
    for (int j = tid; j < N_MOLS; j += 512) {
        float cse = aload(&col_se[j]);
        float ps  = aload(&pos_sim[j]);
        m2p += SHIFT + __logf(cse) - ps;
    }
    for (int i = tid; i < N_PROTS; i += 512) {
        const int j0 = i << 3;
        float sarr[8], pc[8], pr[8];
#pragma unroll
        for (int p = 0; p < 8; ++p) {
            sarr[p] = aload(&pos_sim[j0 + p]);
            pr[p]   = pic50[(size_t)i * N_MOLS + j0 + p];
            float x = (pr[p] - 2.0f) * 0.125f;
            pc[p] = fminf(fmaxf(x, 0.f), 1.f);
            prelu += fmaxf(sarr[p], 0.f);
        }
        float wsum = 1e-8f;
#pragma unroll
        for (int p = 0; p < 8; ++p) wsum += pc[p];
        float lse = SHIFT + __logf(aload(&row_se[i]));
        float accp = 0.f;
#pragma unroll
        for (int p = 0; p < 8; ++p) accp += pc[p] * (lse - sarr[p]);
        p2m += accp / wsum;
#pragma unroll
        for (int a = 0; a < 8; ++a)
#pragma unroll
            for (int b = a + 1; b < 8; ++b) {
                float dp = pr[a] - pr[b];
                float ds = sarr[a] - sarr[b];
                float v = (dp > 0.f) ? fmaxf(MARGIN - ds, 0.f)
                        : ((dp < 0.f) ? fmaxf(MARGIN + ds, 0.f) : 0.f);
                rank += v;
            }
    }
#pragma unroll
    for (int m = 1; m < 64; m <<= 1) {
        m2p   += __shfl_xor(m2p, m);
        p2m   += __shfl_xor(p2m, m);
        rank  += __shfl_xor(rank, m);
        prelu += __shfl_xor(prelu, m);
    }
    if (lane == 0) { rbuf2[wave][0] = m2p; rbuf2[wave][1] = p2m;
                     rbuf2[wave][2] = rank; rbuf2[wave][3] = prelu; }
    __syncthreads();
    if (tid == 0) {
        float a = 0, b = 0, c = 0, d = 0;
        for (int w = 0; w < 8; ++w) { a += rbuf2[w][0]; b += rbuf2[w][1];
                                      c += rbuf2[w][2]; d += rbuf2[w][3]; }
        float s0 = aload(&scalars[0]);          // total relu-sum (all blocks)
        float relu_neg = s0 - d;
        float p2mv  = b / (float)N_PROTS;
        float m2pv  = a / (float)N_MOLS;
        float rankv = c / ((float)N_PROTS * 28.0f);
        float negv  = relu_neg / ((float)N_PROTS * (float)N_MOLS);
        out[0] = p2mv + m2pv + 0.5f * rankv + 0.1f * negv;
        out[1] = p2mv;
        out[2] = m2pv;
        out[3] = rankv;
        out[4] = negv;
    }
}

// ---------------- fallback path (small ws): known-good fp32 GEMM -------------
__global__ __launch_bounds__(256, 2)
void sim_pass(const float* __restrict__ prot, const float* __restrict__ mol,
              const float* __restrict__ scale_p,
              float* __restrict__ row_se, float* __restrict__ col_se,
              float* __restrict__ pos_sim, float* __restrict__ scalars)
{
    __shared__ unsigned short As[128][32];
    __shared__ unsigned short Bs[128][32];
    __shared__ float redBuf[4];

    const int tid = threadIdx.x;
    const int rowBase = blockIdx.y * 128;
    const int colBase = blockIdx.x * 128;
    const int wave = tid >> 6;
    const int lane = tid & 63;
    const int wr = (wave >> 1) * 64;
    const int wc = (wave & 1) * 64;
    const int l15 = lane & 15;
    const int q   = lane >> 4;

    f32x4 acc[4][4];
#pragma unroll
    for (int i = 0; i < 4; ++i)
#pragma unroll
        for (int j = 0; j < 4; ++j) acc[i][j] = (f32x4){0.f, 0.f, 0.f, 0.f};

    const float* aBase = prot + (size_t)rowBase * DIM;
    const float* bBase = mol  + (size_t)colBase * DIM;
    float4 aReg[4], bReg[4];
#pragma unroll
    for (int i = 0; i < 4; ++i) {
        int f = tid + 256 * i;
        int row = f >> 3, c4 = f & 7;
        aReg[i] = *(const float4*)(aBase + (size_t)row * DIM + (c4 << 2));
        bReg[i] = *(const float4*)(bBase + (size_t)row * DIM + (c4 << 2));
    }
#pragma unroll 1
    for (int s = 0; s < DIM / 32; ++s) {
#pragma unroll
        for (int i = 0; i < 4; ++i) {
            int f = tid + 256 * i;
            int row = f >> 3, c4 = f & 7;
            us4 av, bv;
            av.x = bf16rnd(aReg[i].x); av.y = bf16rnd(aReg[i].y);
            av.z = bf16rnd(aReg[i].z); av.w = bf16rnd(aReg[i].w);
            bv.x = bf16rnd(bReg[i].x); bv.y = bf16rnd(bReg[i].y);
            bv.z = bf16rnd(bReg[i].z); bv.w = bf16rnd(bReg[i].w);
            *(us4*)&As[row][c4 << 2] = av;
            *(us4*)&Bs[row][c4 << 2] = bv;
        }
        __syncthreads();
        if (s + 1 < DIM / 32) {
            int k0 = (s + 1) * 32;
#pragma unroll
            for (int i = 0; i < 4; ++i) {
                int f = tid + 256 * i;
                int row = f >> 3, c4 = f & 7;
                aReg[i] = *(const float4*)(aBase + (size_t)row * DIM + k0 + (c4 << 2));
                bReg[i] = *(const float4*)(bBase + (size_t)row * DIM + k0 + (c4 << 2));
            }
        }
        short8 aF[4], bF[4];
#pragma unroll
        for (int mi = 0; mi < 4; ++mi) aF[mi] = *(const short8*)&As[wr + mi * 16 + l15][q * 8];
#pragma unroll
        for (int ni = 0; ni < 4; ++ni) bF[ni] = *(const short8*)&Bs[wc + ni * 16 + l15][q * 8];
#pragma unroll
        for (int mi = 0; mi < 4; ++mi)
#pragma unroll
            for (int ni = 0; ni < 4; ++ni)
                acc[mi][ni] = __builtin_amdgcn_mfma_f32_16x16x32_bf16(aF[mi], bF[ni], acc[mi][ni], 0, 0, 0);
        __syncthreads();
    }

    const float scale = scale_p[0];
    float rsum[4][4];
    float csum[4] = {0.f, 0.f, 0.f, 0.f};
    float rl = 0.f;
#pragma unroll
    for (int mi = 0; mi < 4; ++mi)
#pragma unroll
        for (int r = 0; r < 4; ++r) rsum[mi][r] = 0.f;
#pragma unroll
    for (int mi = 0; mi < 4; ++mi) {
#pragma unroll
        for (int ni = 0; ni < 4; ++ni) {
#pragma unroll
            for (int r = 0; r < 4; ++r) {
                float sim = acc[mi][ni][r] * scale;
                float e = __expf(sim - SHIFT);
                rsum[mi][r] += e;
                csum[ni] += e;
                rl += fmaxf(sim, 0.f);
                int rg = rowBase + wr + mi * 16 + q * 4 + r;
                int cg = colBase + wc + ni * 16 + l15;
                if ((cg >> 3) == rg) pos_sim[cg] = sim;
            }
        }
    }
#pragma unroll
    for (int mi = 0; mi < 4; ++mi) {
#pragma unroll
        for (int r = 0; r < 4; ++r) {
            float v = rsum[mi][r];
            v += __shfl_xor(v, 1); v += __shfl_xor(v, 2);
            v += __shfl_xor(v, 4); v += __shfl_xor(v, 8);
            if (l15 == 0)
                atomicAdd(&row_se[rowBase + wr + mi * 16 + q * 4 + r], v);
        }
    }
#pragma unroll
    for (int ni = 0; ni < 4; ++ni) {
        float v = csum[ni];
        v += __shfl_xor(v, 16); v += __shfl_xor(v, 32);
        if (q == 0)
            atomicAdd(&col_se[colBase + wc + ni * 16 + l15], v);
    }
#pragma unroll
    for (int m = 1; m < 64; m <<= 1) rl += __shfl_xor(rl, m);
    if (lane == 0) redBuf[wave] = rl;
    __syncthreads();
    if (tid == 0)
        atomicAdd(&scalars[0], redBuf[0] + redBuf[1] + redBuf[2] + redBuf[3]);
}

__global__ __launch_bounds__(256)
void finalize_mb(const float* __restrict__ row_se, const float* __restrict__ col_se,
                 const float* __restrict__ pos_sim, const float* __restrict__ pic50,
                 float* __restrict__ scalars, float* __restrict__ out)
{
    int j = blockIdx.x * 256 + threadIdx.x;
    float m2p = SHIFT + __logf(col_se[j]) - pos_sim[j];

    float p2m = 0.f, rank = 0.f, prelu = 0.f;
    if ((j & 7) == 0) {
        int i = j >> 3;
        float s[8], pc[8], pr[8];
#pragma unroll
        for (int p = 0; p < 8; ++p) {
            s[p]  = pos_sim[j + p];
            pr[p] = pic50[(size_t)i * N_MOLS + j + p];
            float x = (pr[p] - 2.0f) * 0.125f;
            pc[p] = fminf(fmaxf(x, 0.f), 1.f);
            prelu += fmaxf(s[p], 0.f);
        }
        float wsum = 1e-8f;
#pragma unroll
        for (int p = 0; p < 8; ++p) wsum += pc[p];
        float lse = SHIFT + __logf(row_se[i]);
        float accp = 0.f;
#pragma unroll
        for (int p = 0; p < 8; ++p) accp += pc[p] * (lse - s[p]);
        p2m = accp / wsum;
#pragma unroll
        for (int a = 0; a < 8; ++a)
#pragma unroll
            for (int b = a + 1; b < 8; ++b) {
                float dp = pr[a] - pr[b];
                float ds = s[a] - s[b];
                float v = (dp > 0.f) ? fmaxf(MARGIN - ds, 0.f)
                        : ((dp < 0.f) ? fmaxf(MARGIN + ds, 0.f) : 0.f);
                rank += v;
            }
    }
#pragma unroll
    for (int m = 1; m < 64; m <<= 1) {
        m2p   += __shfl_xor(m2p, m);
        p2m   += __shfl_xor(p2m, m);
        rank  += __shfl_xor(rank, m);
        prelu += __shfl_xor(prelu, m);
    }
    __shared__ float rbuf[4][4];
    const int wave = threadIdx.x >> 6, lane = threadIdx.x & 63;
    if (lane == 0) { rbuf[wave][0] = m2p; rbuf[wave][1] = p2m;
                     rbuf[wave][2] = rank; rbuf[wave][3] = prelu; }
    __syncthreads();
    if (threadIdx.x == 0) {
        float a = 0, b = 0, c = 0, d = 0;
        for (int w = 0; w < 4; ++w) { a += rbuf[w][0]; b += rbuf[w][1];
                                      c += rbuf[w][2]; d += rbuf[w][3]; }
        atomicAdd(&scalars[2], a);
        atomicAdd(&scalars[1], b);
        atomicAdd(&scalars[3], c);
        atomicAdd(&scalars[4], d);
        __threadfence();
        float old = atomicAdd(&scalars[7], 1.0f);
        if (old == (float)(N_MOLS / 256 - 1)) {
            float s0 = atomicAdd(&scalars[0], 0.0f);
            float s1 = atomicAdd(&scalars[1], 0.0f);
            float s2 = atomicAdd(&scalars[2], 0.0f);
            float s3 = atomicAdd(&scalars[3], 0.0f);
            float s4 = atomicAdd(&scalars[4], 0.0f);
            float relu_neg = s0 - s4;
            float p2mv  = s1 / (float)N_PROTS;
            float m2pv  = s2 / (float)N_MOLS;
            float rankv = s3 / ((float)N_PROTS * 28.0f);
            float negv  = relu_neg / ((float)N_PROTS * (float)N_MOLS);
            out[0] = p2mv + m2pv + 0.5f * rankv + 0.1f * negv;
            out[1] = p2mv;
            out[2] = m2pv;
            out[3] = rankv;
            out[4] = negv;
        }
    }
}

extern "C" void kernel_launch(void* const* d_in, const int* in_sizes, int n_in,
                              void* d_out, int out_size, void* d_ws, size_t ws_size,
                              hipStream_t stream) {
    const float* prot   = (const float*)d_in[0];
    const float* mol    = (const float*)d_in[1];
    const float* pic50  = (const float*)d_in[3];
    const float* lscale = (const float*)d_in[4];

    float* ws      = (float*)d_ws;
    float* scalars = ws + 34816;

    if (ws_size >= WS_NEED) {
        unsigned short* protBf = (unsigned short*)((char*)d_ws + PROT_BF_OFF_B);
        unsigned short* molBf  = (unsigned short*)((char*)d_ws + MOL_BF_OFF_B);
        // counters/scalars must be pre-zeroed (in-kernel zeroing would race
        // with barrier arrivals); 32 B memset is the only extra dispatch.
        hipMemsetAsync(scalars, 0, 8 * sizeof(float), stream);
        fused_all<<<256, 512, 0, stream>>>(prot, mol, pic50, lscale,
                                           protBf, molBf, ws, (float*)d_out);
    } else {
        hipMemsetAsync(d_ws, 0, (size_t)ACC_FLOATS * sizeof(float), stream);
        float* row_se  = ws;
        float* col_se  = ws + 2048;
        float* pos_sim = ws + 2048 + 16384;
        dim3 grid(N_MOLS / 128, N_PROTS / 128);
        sim_pass<<<grid, 256, 0, stream>>>(prot, mol, lscale, row_se, col_se, pos_sim, scalars);
        finalize_mb<<<N_MOLS / 256, 256, 0, stream>>>(row_se, col_se, pos_sim, pic50, scalars, (float*)d_out);
    }
}

// Round 6
// 381.713 us; speedup vs baseline: 1.3808x; 1.3808x over previous
//
#include <hip/hip_runtime.h>
#include <hip/hip_bf16.h>
#include <math.h>

#define N_PROTS 2048
#define N_MOLS  16384
#define DIM     768
#define SHIFT   16.0f
#define MARGIN  0.5f

typedef __attribute__((ext_vector_type(8))) short short8;
typedef __attribute__((ext_vector_type(4))) float f32x4;
typedef __attribute__((ext_vector_type(4))) unsigned short us4;
typedef __attribute__((ext_vector_type(8))) unsigned short us8;

__device__ __forceinline__ unsigned short bf16rnd(float x) {
    unsigned int u = __float_as_uint(x);
    u += 0x7fffu + ((u >> 16) & 1u);   // round-to-nearest-even
    return (unsigned short)(u >> 16);
}

__device__ __forceinline__ void gload16(const void* g, void* l) {
    __builtin_amdgcn_global_load_lds(
        (const __attribute__((address_space(1))) unsigned int*)g,
        (__attribute__((address_space(3))) unsigned int*)l, 16, 0, 0);
}

__device__ __forceinline__ int sig4(int x) { return (x + (x >> 2)) & 3; }

// ws layout:
//  floats [0, 34824): 0..2048 row_sumexp | 2048..18432 col_sumexp |
//                     18432..34816 pos_sim | 34816..34824 scalars
//  scalars: [0]=relu-sum [1..4]=loss partials [7]=finalize ticket
//  then 16B-aligned: protBf (2048*768 bf16), molBf (16384*768 bf16)
#define ACC_FLOATS 34824
#define PROT_BF_OFF_B 139296ull                      // 34824*4, 16B aligned
#define PROT_BF_BYTES (2048ull*768*2)
#define MOL_BF_OFF_B  (PROT_BF_OFF_B + PROT_BF_BYTES)
#define MOL_BF_BYTES  (16384ull*768*2)
#define WS_NEED       (MOL_BF_OFF_B + MOL_BF_BYTES)  // ~28.5 MB

// -------- one-shot fp32 -> bf16 conversion (+ fused ws zeroing) -----------
__global__ __launch_bounds__(256)
void convert_bf16(const float* __restrict__ prot, const float* __restrict__ mol,
                  unsigned short* __restrict__ protBf, unsigned short* __restrict__ molBf,
                  float* __restrict__ wsZero)
{
    const size_t PROT_G = (size_t)N_PROTS * DIM / 8;   // 16B chunks
    size_t t = (size_t)blockIdx.x * 256 + threadIdx.x;
    if (t < (ACC_FLOATS + 3) / 4) {
        float4 z = {0.f, 0.f, 0.f, 0.f};
        ((float4*)wsZero)[t] = z;
    }
    const float* src;
    unsigned short* dst;
    if (t < PROT_G) { src = prot + t * 8; dst = protBf + t * 8; }
    else            { size_t u = t - PROT_G; src = mol + u * 8; dst = molBf + u * 8; }
    float4 v0 = ((const float4*)src)[0];
    float4 v1 = ((const float4*)src)[1];
    us8 o;
    o[0] = bf16rnd(v0.x); o[1] = bf16rnd(v0.y); o[2] = bf16rnd(v0.z); o[3] = bf16rnd(v0.w);
    o[4] = bf16rnd(v1.x); o[5] = bf16rnd(v1.y); o[6] = bf16rnd(v1.z); o[7] = bf16rnd(v1.w);
    *(us8*)dst = o;
}

// ---- bf16 GEMM v5b: 256x256, BK=32, 8 waves, depth-2 counted pipe (RACE FIX) --
// v5's NaN: ds_reads were issued between vmcnt(4) and s_barrier -- own-wave
// loads retired but OTHER waves' stage loads (which fill the rows this wave
// reads) were not. Fix: reads strictly AFTER {vmcnt(4); s_barrier}.
// 3 LDS buffers (96 KB): read kt | in-flight kt+1 | staging kt+2.
// One barrier per K-tile; two sub-phases, each:
//   {ds_read cluster ; stage half-tile ; lgkmcnt(0) ; sched_barrier(0) ;
//    setprio(1) ; 16 MFMA ; setprio(0)}
// WAR safety of staging into (kt+2)%3 (= buffer of kt-1): every wave's reads
// of buffer kt-1 retired at its phase-1 lgkmcnt(0), which precedes its
// arrival at iteration kt's barrier; stage is issued after that barrier.
__global__ __launch_bounds__(512)
void sim_pass_bf16_v5b(const unsigned short* __restrict__ protBf,
                       const unsigned short* __restrict__ molBf,
                       const float* __restrict__ scale_p,
                       float* __restrict__ row_se, float* __restrict__ col_se,
                       float* __restrict__ pos_sim, float* __restrict__ scalars)
{
    __shared__ unsigned short As[3][256][32];   // 48 KB
    __shared__ unsigned short Bs[3][256][32];   // 48 KB
    __shared__ float redBuf[8];

    const int tid = threadIdx.x;
    // XCD-aware bijective swizzle (grid 512, nwg%8==0)
    const int bid  = blockIdx.x;
    const int xcd  = bid & 7;
    const int sl8  = bid >> 3;                 // 0..63
    const int bx   = xcd * 8 + (sl8 & 7);      // 0..63  (col tile)
    const int by   = sl8 >> 3;                 // 0..7   (row tile)
    const int rowBase = by * 256;
    const int colBase = bx * 256;

    const int wave = tid >> 6;
    const int lane = tid & 63;
    const int wm = wave >> 2;                  // 0..1  -> 128-row half
    const int wn = wave & 3;                   // 0..3  -> 64-col slice
    const int l15 = lane & 15;
    const int q   = lane >> 4;

    // staging geometry (pre-swizzled global source; LDS written linearly)
    const int rsub = lane >> 2;                // 0..15 row within 16-row group
    const int cs   = lane & 3;                 // LDS 16B chunk slot
    const int csrc = (cs ^ sig4(rsub)) << 3;   // halfword offset of source chunk
    const unsigned short* aP =
        protBf + (size_t)(rowBase + wave * 32 + rsub) * DIM + csrc;
    const unsigned short* bP =
        molBf  + (size_t)(colBase + wave * 32 + rsub) * DIM + csrc;

#define STAGE_A(sl, kt) do { \
    gload16(aP + (size_t)(kt) * 32,                    &As[sl][wave * 32][0]);      \
    gload16(aP + (size_t)(kt) * 32 + (size_t)16 * DIM, &As[sl][wave * 32 + 16][0]); \
} while (0)
#define STAGE_B(sl, kt) do { \
    gload16(bP + (size_t)(kt) * 32,                    &Bs[sl][wave * 32][0]);      \
    gload16(bP + (size_t)(kt) * 32 + (size_t)16 * DIM, &Bs[sl][wave * 32 + 16][0]); \
} while (0)

    f32x4 acc[8][4];
#pragma unroll
    for (int i = 0; i < 8; ++i)
#pragma unroll
        for (int j = 0; j < 4; ++j) acc[i][j] = (f32x4){0.f, 0.f, 0.f, 0.f};

    // prologue: stage K-tiles 0 and 1 (8 loads/thread, queue oldest-first A0,B0,A1,B1)
    STAGE_A(0, 0); STAGE_B(0, 0);
    STAGE_A(1, 1); STAGE_B(1, 1);

    // fragment read geometry: slot s of row r holds global chunk s^sig4(r&15)
    const int fArow = wm * 128 + l15;          // + mi*16
    const int fBrow = wn * 64 + l15;           // + ni*16
    const int fsw   = (q ^ sig4(l15)) << 3;    // halfword offset (16B aligned)

#pragma unroll 1
    for (int kt = 0; kt < 24; ++kt) {
        const int db  = kt % 3;
        const int s2  = (kt + 2) % 3;          // buffer of kt-1: reads retired
        const int kt2 = (kt + 2 < 24) ? (kt + 2) : (kt - 10);  // tail dummy

        // counted boundary wait: tile kt's 4 loads (all waves) landed;
        // tile kt+1's 4 stay in flight. Reads only after the barrier.
        asm volatile("s_waitcnt vmcnt(4)" ::: "memory");
        __builtin_amdgcn_s_barrier();
        __builtin_amdgcn_sched_barrier(0);

        // ---------- sub-phase 0: B all + A lo ----------
        short8 aF[4], bF[4];
#pragma unroll
        for (int ni = 0; ni < 4; ++ni)
            bF[ni] = *(const short8*)&Bs[db][fBrow + ni * 16][fsw];
#pragma unroll
        for (int mi = 0; mi < 4; ++mi)
            aF[mi] = *(const short8*)&As[db][fArow + mi * 16][fsw];
        STAGE_A(s2, kt2);
        asm volatile("s_waitcnt lgkmcnt(0)" ::: "memory");
        __builtin_amdgcn_sched_barrier(0);
        __builtin_amdgcn_s_setprio(1);
#pragma unroll
        for (int mi = 0; mi < 4; ++mi)
#pragma unroll
            for (int ni = 0; ni < 4; ++ni)
                acc[mi][ni] = __builtin_amdgcn_mfma_f32_16x16x32_bf16(
                    aF[mi], bF[ni], acc[mi][ni], 0, 0, 0);
        __builtin_amdgcn_s_setprio(0);

        // ---------- sub-phase 1: A hi (bF reused) ----------
#pragma unroll
        for (int mi = 0; mi < 4; ++mi)
            aF[mi] = *(const short8*)&As[db][fArow + 64 + mi * 16][fsw];
        STAGE_B(s2, kt2);
        asm volatile("s_waitcnt lgkmcnt(0)" ::: "memory");
        __builtin_amdgcn_sched_barrier(0);
        __builtin_amdgcn_s_setprio(1);
#pragma unroll
        for (int mi = 0; mi < 4; ++mi)
#pragma unroll
            for (int ni = 0; ni < 4; ++ni)
                acc[4 + mi][ni] = __builtin_amdgcn_mfma_f32_16x16x32_bf16(
                    aF[mi], bF[ni], acc[4 + mi][ni], 0, 0, 0);
        __builtin_amdgcn_s_setprio(0);
    }
    asm volatile("s_waitcnt vmcnt(0)" ::: "memory");   // retire dummy stages
#undef STAGE_A
#undef STAGE_B

    // ---------------- epilogue ----------------
    const float scale = scale_p[0];
    float csum[4] = {0.f, 0.f, 0.f, 0.f};
    float rl = 0.f;
#pragma unroll
    for (int mi = 0; mi < 8; ++mi) {
        float rs[4] = {0.f, 0.f, 0.f, 0.f};
#pragma unroll
        for (int ni = 0; ni < 4; ++ni) {
#pragma unroll
            for (int r = 0; r < 4; ++r) {
                float sim = acc[mi][ni][r] * scale;
                float e = __expf(sim - SHIFT);
                rs[r] += e;
                csum[ni] += e;
                rl += fmaxf(sim, 0.f);
                int rg = rowBase + wm * 128 + mi * 16 + q * 4 + r;
                int cg = colBase + wn * 64 + ni * 16 + l15;
                if ((cg >> 3) == rg) pos_sim[cg] = sim;   // unique writer
            }
        }
#pragma unroll
        for (int r = 0; r < 4; ++r) {
            float v = rs[r];
            v += __shfl_xor(v, 1); v += __shfl_xor(v, 2);
            v += __shfl_xor(v, 4); v += __shfl_xor(v, 8);
            if (l15 == 0)
                atomicAdd(&row_se[rowBase + wm * 128 + mi * 16 + q * 4 + r], v);
        }
    }
#pragma unroll
    for (int ni = 0; ni < 4; ++ni) {
        float v = csum[ni];
        v += __shfl_xor(v, 16); v += __shfl_xor(v, 32);
        if (q == 0)
            atomicAdd(&col_se[colBase + wn * 64 + ni * 16 + l15], v);
    }
#pragma unroll
    for (int m = 1; m < 64; m <<= 1) rl += __shfl_xor(rl, m);
    if (lane == 0) redBuf[wave] = rl;
    __syncthreads();
    if (tid == 0) {
        float sv = 0.f;
#pragma unroll
        for (int w = 0; w < 8; ++w) sv += redBuf[w];
        atomicAdd(&scalars[0], sv);
    }
}

// ---------------- fallback path (small ws): known-good fp32 GEMM -------------
__global__ __launch_bounds__(256, 2)
void sim_pass(const float* __restrict__ prot, const float* __restrict__ mol,
              const float* __restrict__ scale_p,
              float* __restrict__ row_se, float* __restrict__ col_se,
              float* __restrict__ pos_sim, float* __restrict__ scalars)
{
    __shared__ unsigned short As[128][32];
    __shared__ unsigned short Bs[128][32];
    __shared__ float redBuf[4];

    const int tid = threadIdx.x;
    const int rowBase = blockIdx.y * 128;
    const int colBase = blockIdx.x * 128;
    const int wave = tid >> 6;
    const int lane = tid & 63;
    const int wr = (wave >> 1) * 64;
    const int wc = (wave & 1) * 64;
    const int l15 = lane & 15;
    const int q   = lane >> 4;

    f32x4 acc[4][4];
#pragma unroll
    for (int i = 0; i < 4; ++i)
#pragma unroll
        for (int j = 0; j < 4; ++j) acc[i][j] = (f32x4){0.f, 0.f, 0.f, 0.f};

    const float* aBase = prot + (size_t)rowBase * DIM;
    const float* bBase = mol  + (size_t)colBase * DIM;
    float4 aReg[4], bReg[4];
#pragma unroll
    for (int i = 0; i < 4; ++i) {
        int f = tid + 256 * i;
        int row = f >> 3, c4 = f & 7;
        aReg[i] = *(const float4*)(aBase + (size_t)row * DIM + (c4 << 2));
        bReg[i] = *(const float4*)(bBase + (size_t)row * DIM + (c4 << 2));
    }
#pragma unroll 1
    for (int s = 0; s < DIM / 32; ++s) {
#pragma unroll
        for (int i = 0; i < 4; ++i) {
            int f = tid + 256 * i;
            int row = f >> 3, c4 = f & 7;
            us4 av, bv;
            av.x = bf16rnd(aReg[i].x); av.y = bf16rnd(aReg[i].y);
            av.z = bf16rnd(aReg[i].z); av.w = bf16rnd(aReg[i].w);
            bv.x = bf16rnd(bReg[i].x); bv.y = bf16rnd(bReg[i].y);
            bv.z = bf16rnd(bReg[i].z); bv.w = bf16rnd(bReg[i].w);
            *(us4*)&As[row][c4 << 2] = av;
            *(us4*)&Bs[row][c4 << 2] = bv;
        }
        __syncthreads();
        if (s + 1 < DIM / 32) {
            int k0 = (s + 1) * 32;
#pragma unroll
            for (int i = 0; i < 4; ++i) {
                int f = tid + 256 * i;
                int row = f >> 3, c4 = f & 7;
                aReg[i] = *(const float4*)(aBase + (size_t)row * DIM + k0 + (c4 << 2));
                bReg[i] = *(const float4*)(bBase + (size_t)row * DIM + k0 + (c4 << 2));
            }
        }
        short8 aF[4], bF[4];
#pragma unroll
        for (int mi = 0; mi < 4; ++mi) aF[mi] = *(const short8*)&As[wr + mi * 16 + l15][q * 8];
#pragma unroll
        for (int ni = 0; ni < 4; ++ni) bF[ni] = *(const short8*)&Bs[wc + ni * 16 + l15][q * 8];
#pragma unroll
        for (int mi = 0; mi < 4; ++mi)
#pragma unroll
            for (int ni = 0; ni < 4; ++ni)
                acc[mi][ni] = __builtin_amdgcn_mfma_f32_16x16x32_bf16(aF[mi], bF[ni], acc[mi][ni], 0, 0, 0);
        __syncthreads();
    }

    const float scale = scale_p[0];
    float rsum[4][4];
    float csum[4] = {0.f, 0.f, 0.f, 0.f};
    float rl = 0.f;
#pragma unroll
    for (int mi = 0; mi < 4; ++mi)
#pragma unroll
        for (int r = 0; r < 4; ++r) rsum[mi][r] = 0.f;
#pragma unroll
    for (int mi = 0; mi < 4; ++mi) {
#pragma unroll
        for (int ni = 0; ni < 4; ++ni) {
#pragma unroll
            for (int r = 0; r < 4; ++r) {
                float sim = acc[mi][ni][r] * scale;
                float e = __expf(sim - SHIFT);
                rsum[mi][r] += e;
                csum[ni] += e;
                rl += fmaxf(sim, 0.f);
                int rg = rowBase + wr + mi * 16 + q * 4 + r;
                int cg = colBase + wc + ni * 16 + l15;
                if ((cg >> 3) == rg) pos_sim[cg] = sim;
            }
        }
    }
#pragma unroll
    for (int mi = 0; mi < 4; ++mi) {
#pragma unroll
        for (int r = 0; r < 4; ++r) {
            float v = rsum[mi][r];
            v += __shfl_xor(v, 1); v += __shfl_xor(v, 2);
            v += __shfl_xor(v, 4); v += __shfl_xor(v, 8);
            if (l15 == 0)
                atomicAdd(&row_se[rowBase + wr + mi * 16 + q * 4 + r], v);
        }
    }
#pragma unroll
    for (int ni = 0; ni < 4; ++ni) {
        float v = csum[ni];
        v += __shfl_xor(v, 16); v += __shfl_xor(v, 32);
        if (q == 0)
            atomicAdd(&col_se[colBase + wc + ni * 16 + l15], v);
    }
#pragma unroll
    for (int m = 1; m < 64; m <<= 1) rl += __shfl_xor(rl, m);
    if (lane == 0) redBuf[wave] = rl;
    __syncthreads();
    if (tid == 0)
        atomicAdd(&scalars[0], redBuf[0] + redBuf[1] + redBuf[2] + redBuf[3]);
}

// ---- finalize: 64 parallel blocks; last block (ticket) writes the output ----
__global__ __launch_bounds__(256)
void finalize_mb(const float* __restrict__ row_se, const float* __restrict__ col_se,
                 const float* __restrict__ pos_sim, const float* __restrict__ pic50,
                 float* __restrict__ scalars, float* __restrict__ out)
{
    int j = blockIdx.x * 256 + threadIdx.x;   // mol index
    float m2p = SHIFT + __logf(col_se[j]) - pos_sim[j];

    float p2m = 0.f, rank = 0.f, prelu = 0.f;
    if ((j & 7) == 0) {
        int i = j >> 3;
        float s[8], pc[8], pr[8];
#pragma unroll
        for (int p = 0; p < 8; ++p) {
            s[p]  = pos_sim[j + p];
            pr[p] = pic50[(size_t)i * N_MOLS + j + p];
            float x = (pr[p] - 2.0f) * 0.125f;
            pc[p] = fminf(fmaxf(x, 0.f), 1.f);
            prelu += fmaxf(s[p], 0.f);
        }
        float wsum = 1e-8f;
#pragma unroll
        for (int p = 0; p < 8; ++p) wsum += pc[p];
        float lse = SHIFT + __logf(row_se[i]);
        float accp = 0.f;
#pragma unroll
        for (int p = 0; p < 8; ++p) accp += pc[p] * (lse - s[p]);
        p2m = accp / wsum;
#pragma unroll
        for (int a = 0; a < 8; ++a)
#pragma unroll
            for (int b = a + 1; b < 8; ++b) {
                float dp = pr[a] - pr[b];
                float ds = s[a] - s[b];
                float v = (dp > 0.f) ? fmaxf(MARGIN - ds, 0.f)
                        : ((dp < 0.f) ? fmaxf(MARGIN + ds, 0.f) : 0.f);
                rank += v;
            }
    }
#pragma unroll
    for (int m = 1; m < 64; m <<= 1) {
        m2p   += __shfl_xor(m2p, m);
        p2m   += __shfl_xor(p2m, m);
        rank  += __shfl_xor(rank, m);
        prelu += __shfl_xor(prelu, m);
    }
    __shared__ float rbuf[4][4];
    const int wave = threadIdx.x >> 6, lane = threadIdx.x & 63;
    if (lane == 0) { rbuf[wave][0] = m2p; rbuf[wave][1] = p2m;
                     rbuf[wave][2] = rank; rbuf[wave][3] = prelu; }
    __syncthreads();
    if (threadIdx.x == 0) {
        float a = 0, b = 0, c = 0, d = 0;
        for (int w = 0; w < 4; ++w) { a += rbuf[w][0]; b += rbuf[w][1];
                                      c += rbuf[w][2]; d += rbuf[w][3]; }
        atomicAdd(&scalars[2], a);
        atomicAdd(&scalars[1], b);
        atomicAdd(&scalars[3], c);
        atomicAdd(&scalars[4], d);
        __threadfence();
        float old = atomicAdd(&scalars[7], 1.0f);   // ticket
        if (old == (float)(N_MOLS / 256 - 1)) {
            float s0 = atomicAdd(&scalars[0], 0.0f);
            float s1 = atomicAdd(&scalars[1], 0.0f);
            float s2 = atomicAdd(&scalars[2], 0.0f);
            float s3 = atomicAdd(&scalars[3], 0.0f);
            float s4 = atomicAdd(&scalars[4], 0.0f);
            float relu_neg = s0 - s4;
            float p2mv  = s1 / (float)N_PROTS;
            float m2pv  = s2 / (float)N_MOLS;
            float rankv = s3 / ((float)N_PROTS * 28.0f);
            float negv  = relu_neg / ((float)N_PROTS * (float)N_MOLS);
            out[0] = p2mv + m2pv + 0.5f * rankv + 0.1f * negv;
            out[1] = p2mv;
            out[2] = m2pv;
            out[3] = rankv;
            out[4] = negv;
        }
    }
}

extern "C" void kernel_launch(void* const* d_in, const int* in_sizes, int n_in,
                              void* d_out, int out_size, void* d_ws, size_t ws_size,
                              hipStream_t stream) {
    const float* prot   = (const float*)d_in[0];
    const float* mol    = (const float*)d_in[1];
    const float* pic50  = (const float*)d_in[3];
    const float* lscale = (const float*)d_in[4];

    float* ws      = (float*)d_ws;
    float* row_se  = ws;
    float* col_se  = ws + 2048;
    float* pos_sim = ws + 2048 + 16384;
    float* scalars = ws + 34816;

    if (ws_size >= WS_NEED) {
        unsigned short* protBf = (unsigned short*)((char*)d_ws + PROT_BF_OFF_B);
        unsigned short* molBf  = (unsigned short*)((char*)d_ws + MOL_BF_OFF_B);
        size_t groups = ((size_t)N_PROTS + N_MOLS) * DIM / 8;   // 1,769,472
        convert_bf16<<<(unsigned)(groups / 256), 256, 0, stream>>>(prot, mol, protBf, molBf, ws);
        sim_pass_bf16_v5b<<<512, 512, 0, stream>>>(protBf, molBf, lscale, row_se, col_se, pos_sim, scalars);
    } else {
        hipMemsetAsync(d_ws, 0, (size_t)ACC_FLOATS * sizeof(float), stream);
        dim3 grid(N_MOLS / 128, N_PROTS / 128);
        sim_pass<<<grid, 256, 0, stream>>>(prot, mol, lscale, row_se, col_se, pos_sim, scalars);
    }
    finalize_mb<<<N_MOLS / 256, 256, 0, stream>>>(row_se, col_se, pos_sim, pic50, scalars, (float*)d_out);
}

// Round 7
// 356.969 us; speedup vs baseline: 1.4765x; 1.0693x over previous
//
#include <hip/hip_runtime.h>
#include <hip/hip_bf16.h>
#include <math.h>

#define N_PROTS 2048
#define N_MOLS  16384
#define DIM     768
#define SHIFT   16.0f
#define MARGIN  0.5f

typedef __attribute__((ext_vector_type(8))) short short8;
typedef __attribute__((ext_vector_type(4))) float f32x4;
typedef __attribute__((ext_vector_type(4))) unsigned short us4;
typedef __attribute__((ext_vector_type(4))) int i32x4;
typedef __attribute__((ext_vector_type(8))) int i32x8;

__device__ __forceinline__ unsigned short bf16rnd(float x) {
    unsigned int u = __float_as_uint(x);
    u += 0x7fffu + ((u >> 16) & 1u);
    return (unsigned short)(u >> 16);
}

__device__ __forceinline__ void gload16(const void* g, void* l) {
    __builtin_amdgcn_global_load_lds(
        (const __attribute__((address_space(1))) unsigned int*)g,
        (__attribute__((address_space(3))) unsigned int*)l, 16, 0, 0);
}

// ws layout:
//  floats [0, 34824): 0..2048 row_sumexp | 2048..18432 col_sumexp |
//                     18432..34816 pos_sim | 34816..34824 scalars
//  scalars: [0]=relu-sum [1..4]=loss partials [7]=finalize ticket
//  then 16B-aligned: protF8 (2048*768 fp8), molF8 (16384*768 fp8)
#define ACC_FLOATS 34824
#define PROT_F8_OFF_B 139296ull                      // 34824*4, 16B aligned
#define PROT_F8_BYTES (2048ull*768)
#define MOL_F8_OFF_B  (PROT_F8_OFF_B + PROT_F8_BYTES)
#define MOL_F8_BYTES  (16384ull*768)
#define WS_NEED       (MOL_F8_OFF_B + MOL_F8_BYTES)  // ~14.3 MB

// ---- one-shot fp32 -> fp8 e4m3 (OCP) conversion + fused ws zeroing --------
// HW v_cvt_pk_fp8_f32 = round-to-nearest-even, saturating; inputs are
// L2-normalized (|x| < 1) so no overflow, subnormal tail negligible.
__global__ __launch_bounds__(256)
void convert_fp8(const float* __restrict__ prot, const float* __restrict__ mol,
                 unsigned char* __restrict__ protF8, unsigned char* __restrict__ molF8,
                 float* __restrict__ wsZero)
{
    const size_t PROT_G = (size_t)N_PROTS * DIM / 8;   // 8-elem groups
    size_t t = (size_t)blockIdx.x * 256 + threadIdx.x;
    if (t < (ACC_FLOATS + 3) / 4) {
        float4 z = {0.f, 0.f, 0.f, 0.f};
        ((float4*)wsZero)[t] = z;
    }
    const float* src;
    unsigned char* dst;
    if (t < PROT_G) { src = prot + t * 8; dst = protF8 + t * 8; }
    else            { size_t u = t - PROT_G; src = mol + u * 8; dst = molF8 + u * 8; }
    float4 v0 = ((const float4*)src)[0];
    float4 v1 = ((const float4*)src)[1];
    int w0 = __builtin_amdgcn_cvt_pk_fp8_f32(v0.x, v0.y, 0,  false);
    w0     = __builtin_amdgcn_cvt_pk_fp8_f32(v0.z, v0.w, w0, true);
    int w1 = __builtin_amdgcn_cvt_pk_fp8_f32(v1.x, v1.y, 0,  false);
    w1     = __builtin_amdgcn_cvt_pk_fp8_f32(v1.z, v1.w, w1, true);
    int2 o; o.x = w0; o.y = w1;
    *(int2*)dst = o;                                   // 8 fp8 bytes
}

// ---- fp8 GEMM v6: 256x256 tile, 8 waves, MX-scaled K=128 MFMA, 6 K-tiles ----
// mfma_scale_f32_16x16x128_f8f6f4 with all scales = 0x7F (E8M0 1.0) = plain
// fp8 matmul at 2x bf16 rate (m148 ladder: +64% on this structure family).
// Halves LDS-read bytes AND MFMA cycles; quarters K-tile count (24->6), so
// per-tile drain/barrier events collapse. 2-buffer LDS (128 KB), simple
// __syncthreads() drain per K-tile (v1-proven); stage-next issued right after
// the barrier so its HBM/L2 latency hides under the ~whole tile body.
// Correctness note: any K-permutation applied identically to A and B
// fragments is matmul-invariant, so the fragment K-layout guess is safe.
// LDS swizzle: slot c (16B) of row r holds global chunk c ^ (r&7); fragment
// reads use slot (2q+j) ^ (l15&7) -> 8 slots x 2 rows = 2-way = free.
__global__ __launch_bounds__(512)
void sim_pass_fp8(const unsigned char* __restrict__ protF8,
                  const unsigned char* __restrict__ molF8,
                  const float* __restrict__ scale_p,
                  float* __restrict__ row_se, float* __restrict__ col_se,
                  float* __restrict__ pos_sim, float* __restrict__ scalars)
{
    __shared__ unsigned char As[2][256][128];   // 64 KB
    __shared__ unsigned char Bs[2][256][128];   // 64 KB
    __shared__ float redBuf[8];

    const int tid = threadIdx.x;
    // XCD-aware bijective swizzle (grid 512, nwg%8==0)
    const int bid  = blockIdx.x;
    const int xcd  = bid & 7;
    const int sl8  = bid >> 3;                 // 0..63
    const int bx   = xcd * 8 + (sl8 & 7);      // 0..63  (col tile)
    const int by   = sl8 >> 3;                 // 0..7   (row tile)
    const int rowBase = by * 256;
    const int colBase = bx * 256;

    const int wave = tid >> 6;
    const int lane = tid & 63;
    const int wm = wave >> 2;                  // 0..1  -> 128-row half
    const int wn = wave & 3;                   // 0..3  -> 64-col slice
    const int l15 = lane & 15;
    const int q   = lane >> 4;

    // staging: per gload, 8 rows x 128 B; lane -> row lane>>3, chunk lane&7.
    // source chunk pre-swizzled: (c ^ r8) so linear LDS holds swizzled layout.
    const int r8    = lane >> 3;               // 0..7
    const int c8    = lane & 7;
    const int srcsw = ((c8 ^ r8) << 4);        // byte offset in 128B row-block
    const unsigned char* aP =
        protF8 + (size_t)(rowBase + wave * 32 + r8) * DIM + srcsw;
    const unsigned char* bP =
        molF8  + (size_t)(colBase + wave * 32 + r8) * DIM + srcsw;

#define STAGE(buf, kt) do {                                                   \
    _Pragma("unroll")                                                         \
    for (int i2 = 0; i2 < 4; ++i2) {                                          \
        gload16(aP + (size_t)(kt) * 128 + (size_t)i2 * 8 * DIM,               \
                &As[buf][wave * 32 + i2 * 8][0]);                             \
        gload16(bP + (size_t)(kt) * 128 + (size_t)i2 * 8 * DIM,               \
                &Bs[buf][wave * 32 + i2 * 8][0]);                             \
    }                                                                         \
} while (0)

    f32x4 acc[8][4];
#pragma unroll
    for (int i = 0; i < 8; ++i)
#pragma unroll
        for (int j = 0; j < 4; ++j) acc[i][j] = (f32x4){0.f, 0.f, 0.f, 0.f};

    STAGE(0, 0);                               // prologue

    // fragment geometry: lane holds 32 contiguous K-bytes (one scale block)
    const int fArow = wm * 128 + l15;          // + mi*16
    const int fBrow = wn * 64 + l15;           // + ni*16
    const int s0 = ((2 * q)     ^ (l15 & 7)) << 4;   // swizzled 16B slots
    const int s1 = ((2 * q + 1) ^ (l15 & 7)) << 4;

#pragma unroll 1
    for (int kt = 0; kt < 6; ++kt) {
        const int cur = kt & 1, nxt = cur ^ 1;
        __syncthreads();                       // vmcnt0+lgkm0+barrier: kt ready
        if (kt + 1 < 6) STAGE(nxt, kt + 1);    // latency hides under body

        i32x8 bF[4];
#pragma unroll
        for (int ni = 0; ni < 4; ++ni) {
            const unsigned char* rp = &Bs[cur][fBrow + ni * 16][0];
            i32x4 lo = *(const i32x4*)(rp + s0);
            i32x4 hi = *(const i32x4*)(rp + s1);
            bF[ni] = (i32x8){lo[0], lo[1], lo[2], lo[3], hi[0], hi[1], hi[2], hi[3]};
        }
        __builtin_amdgcn_s_setprio(1);
#pragma unroll
        for (int mi = 0; mi < 8; ++mi) {
            const unsigned char* rp = &As[cur][fArow + mi * 16][0];
            i32x4 lo = *(const i32x4*)(rp + s0);
            i32x4 hi = *(const i32x4*)(rp + s1);
            i32x8 aF = (i32x8){lo[0], lo[1], lo[2], lo[3], hi[0], hi[1], hi[2], hi[3]};
#pragma unroll
            for (int ni = 0; ni < 4; ++ni)
                acc[mi][ni] = __builtin_amdgcn_mfma_scale_f32_16x16x128_f8f6f4(
                    aF, bF[ni], acc[mi][ni], 0, 0,
                    0, 0x7F7F7F7F, 0, 0x7F7F7F7F);   // scales = 1.0
        }
        __builtin_amdgcn_s_setprio(0);
    }
#undef STAGE

    // ---------------- epilogue (C/D layout shape-determined: same as 16x16) --
    const float scale = scale_p[0];
    float csum[4] = {0.f, 0.f, 0.f, 0.f};
    float rl = 0.f;
#pragma unroll
    for (int mi = 0; mi < 8; ++mi) {
        float rs[4] = {0.f, 0.f, 0.f, 0.f};
#pragma unroll
        for (int ni = 0; ni < 4; ++ni) {
#pragma unroll
            for (int r = 0; r < 4; ++r) {
                float sim = acc[mi][ni][r] * scale;
                float e = __expf(sim - SHIFT);
                rs[r] += e;
                csum[ni] += e;
                rl += fmaxf(sim, 0.f);
                int rg = rowBase + wm * 128 + mi * 16 + q * 4 + r;
                int cg = colBase + wn * 64 + ni * 16 + l15;
                if ((cg >> 3) == rg) pos_sim[cg] = sim;   // unique writer
            }
        }
#pragma unroll
        for (int r = 0; r < 4; ++r) {
            float v = rs[r];
            v += __shfl_xor(v, 1); v += __shfl_xor(v, 2);
            v += __shfl_xor(v, 4); v += __shfl_xor(v, 8);
            if (l15 == 0)
                atomicAdd(&row_se[rowBase + wm * 128 + mi * 16 + q * 4 + r], v);
        }
    }
#pragma unroll
    for (int ni = 0; ni < 4; ++ni) {
        float v = csum[ni];
        v += __shfl_xor(v, 16); v += __shfl_xor(v, 32);
        if (q == 0)
            atomicAdd(&col_se[colBase + wn * 64 + ni * 16 + l15], v);
    }
#pragma unroll
    for (int m = 1; m < 64; m <<= 1) rl += __shfl_xor(rl, m);
    if (lane == 0) redBuf[wave] = rl;
    __syncthreads();
    if (tid == 0) {
        float sv = 0.f;
#pragma unroll
        for (int w = 0; w < 8; ++w) sv += redBuf[w];
        atomicAdd(&scalars[0], sv);
    }
}

// ---------------- fallback path (small ws): known-good fp32 GEMM -------------
__global__ __launch_bounds__(256, 2)
void sim_pass(const float* __restrict__ prot, const float* __restrict__ mol,
              const float* __restrict__ scale_p,
              float* __restrict__ row_se, float* __restrict__ col_se,
              float* __restrict__ pos_sim, float* __restrict__ scalars)
{
    __shared__ unsigned short As[128][32];
    __shared__ unsigned short Bs[128][32];
    __shared__ float redBuf[4];

    const int tid = threadIdx.x;
    const int rowBase = blockIdx.y * 128;
    const int colBase = blockIdx.x * 128;
    const int wave = tid >> 6;
    const int lane = tid & 63;
    const int wr = (wave >> 1) * 64;
    const int wc = (wave & 1) * 64;
    const int l15 = lane & 15;
    const int q   = lane >> 4;

    f32x4 acc[4][4];
#pragma unroll
    for (int i = 0; i < 4; ++i)
#pragma unroll
        for (int j = 0; j < 4; ++j) acc[i][j] = (f32x4){0.f, 0.f, 0.f, 0.f};

    const float* aBase = prot + (size_t)rowBase * DIM;
    const float* bBase = mol  + (size_t)colBase * DIM;
    float4 aReg[4], bReg[4];
#pragma unroll
    for (int i = 0; i < 4; ++i) {
        int f = tid + 256 * i;
        int row = f >> 3, c4 = f & 7;
        aReg[i] = *(const float4*)(aBase + (size_t)row * DIM + (c4 << 2));
        bReg[i] = *(const float4*)(bBase + (size_t)row * DIM + (c4 << 2));
    }
#pragma unroll 1
    for (int s = 0; s < DIM / 32; ++s) {
#pragma unroll
        for (int i = 0; i < 4; ++i) {
            int f = tid + 256 * i;
            int row = f >> 3, c4 = f & 7;
            us4 av, bv;
            av.x = bf16rnd(aReg[i].x); av.y = bf16rnd(aReg[i].y);
            av.z = bf16rnd(aReg[i].z); av.w = bf16rnd(aReg[i].w);
            bv.x = bf16rnd(bReg[i].x); bv.y = bf16rnd(bReg[i].y);
            bv.z = bf16rnd(bReg[i].z); bv.w = bf16rnd(bReg[i].w);
            *(us4*)&As[row][c4 << 2] = av;
            *(us4*)&Bs[row][c4 << 2] = bv;
        }
        __syncthreads();
        if (s + 1 < DIM / 32) {
            int k0 = (s + 1) * 32;
#pragma unroll
            for (int i = 0; i < 4; ++i) {
                int f = tid + 256 * i;
                int row = f >> 3, c4 = f & 7;
                aReg[i] = *(const float4*)(aBase + (size_t)row * DIM + k0 + (c4 << 2));
                bReg[i] = *(const float4*)(bBase + (size_t)row * DIM + k0 + (c4 << 2));
            }
        }
        short8 aF[4], bF[4];
#pragma unroll
        for (int mi = 0; mi < 4; ++mi) aF[mi] = *(const short8*)&As[wr + mi * 16 + l15][q * 8];
#pragma unroll
        for (int ni = 0; ni < 4; ++ni) bF[ni] = *(const short8*)&Bs[wc + ni * 16 + l15][q * 8];
#pragma unroll
        for (int mi = 0; mi < 4; ++mi)
#pragma unroll
            for (int ni = 0; ni < 4; ++ni)
                acc[mi][ni] = __builtin_amdgcn_mfma_f32_16x16x32_bf16(aF[mi], bF[ni], acc[mi][ni], 0, 0, 0);
        __syncthreads();
    }

    const float scale = scale_p[0];
    float rsum[4][4];
    float csum[4] = {0.f, 0.f, 0.f, 0.f};
    float rl = 0.f;
#pragma unroll
    for (int mi = 0; mi < 4; ++mi)
#pragma unroll
        for (int r = 0; r < 4; ++r) rsum[mi][r] = 0.f;
#pragma unroll
    for (int mi = 0; mi < 4; ++mi) {
#pragma unroll
        for (int ni = 0; ni < 4; ++ni) {
#pragma unroll
            for (int r = 0; r < 4; ++r) {
                float sim = acc[mi][ni][r] * scale;
                float e = __expf(sim - SHIFT);
                rsum[mi][r] += e;
                csum[ni] += e;
                rl += fmaxf(sim, 0.f);
                int rg = rowBase + wr + mi * 16 + q * 4 + r;
                int cg = colBase + wc + ni * 16 + l15;
                if ((cg >> 3) == rg) pos_sim[cg] = sim;
            }
        }
    }
#pragma unroll
    for (int mi = 0; mi < 4; ++mi) {
#pragma unroll
        for (int r = 0; r < 4; ++r) {
            float v = rsum[mi][r];
            v += __shfl_xor(v, 1); v += __shfl_xor(v, 2);
            v += __shfl_xor(v, 4); v += __shfl_xor(v, 8);
            if (l15 == 0)
                atomicAdd(&row_se[rowBase + wr + mi * 16 + q * 4 + r], v);
        }
    }
#pragma unroll
    for (int ni = 0; ni < 4; ++ni) {
        float v = csum[ni];
        v += __shfl_xor(v, 16); v += __shfl_xor(v, 32);
        if (q == 0)
            atomicAdd(&col_se[colBase + wc + ni * 16 + l15], v);
    }
#pragma unroll
    for (int m = 1; m < 64; m <<= 1) rl += __shfl_xor(rl, m);
    if (lane == 0) redBuf[wave] = rl;
    __syncthreads();
    if (tid == 0)
        atomicAdd(&scalars[0], redBuf[0] + redBuf[1] + redBuf[2] + redBuf[3]);
}

// ---- finalize: 64 parallel blocks; last block (ticket) writes the output ----
__global__ __launch_bounds__(256)
void finalize_mb(const float* __restrict__ row_se, const float* __restrict__ col_se,
                 const float* __restrict__ pos_sim, const float* __restrict__ pic50,
                 float* __restrict__ scalars, float* __restrict__ out)
{
    int j = blockIdx.x * 256 + threadIdx.x;   // mol index
    float m2p = SHIFT + __logf(col_se[j]) - pos_sim[j];

    float p2m = 0.f, rank = 0.f, prelu = 0.f;
    if ((j & 7) == 0) {
        int i = j >> 3;
        float s[8], pc[8], pr[8];
#pragma unroll
        for (int p = 0; p < 8; ++p) {
            s[p]  = pos_sim[j + p];
            pr[p] = pic50[(size_t)i * N_MOLS + j + p];
            float x = (pr[p] - 2.0f) * 0.125f;
            pc[p] = fminf(fmaxf(x, 0.f), 1.f);
            prelu += fmaxf(s[p], 0.f);
        }
        float wsum = 1e-8f;
#pragma unroll
        for (int p = 0; p < 8; ++p) wsum += pc[p];
        float lse = SHIFT + __logf(row_se[i]);
        float accp = 0.f;
#pragma unroll
        for (int p = 0; p < 8; ++p) accp += pc[p] * (lse - s[p]);
        p2m = accp / wsum;
#pragma unroll
        for (int a = 0; a < 8; ++a)
#pragma unroll
            for (int b = a + 1; b < 8; ++b) {
                float dp = pr[a] - pr[b];
                float ds = s[a] - s[b];
                float v = (dp > 0.f) ? fmaxf(MARGIN - ds, 0.f)
                        : ((dp < 0.f) ? fmaxf(MARGIN + ds, 0.f) : 0.f);
                rank += v;
            }
    }
#pragma unroll
    for (int m = 1; m < 64; m <<= 1) {
        m2p   += __shfl_xor(m2p, m);
        p2m   += __shfl_xor(p2m, m);
        rank  += __shfl_xor(rank, m);
        prelu += __shfl_xor(prelu, m);
    }
    __shared__ float rbuf[4][4];
    const int wave = threadIdx.x >> 6, lane = threadIdx.x & 63;
    if (lane == 0) { rbuf[wave][0] = m2p; rbuf[wave][1] = p2m;
                     rbuf[wave][2] = rank; rbuf[wave][3] = prelu; }
    __syncthreads();
    if (threadIdx.x == 0) {
        float a = 0, b = 0, c = 0, d = 0;
        for (int w = 0; w < 4; ++w) { a += rbuf[w][0]; b += rbuf[w][1];
                                      c += rbuf[w][2]; d += rbuf[w][3]; }
        atomicAdd(&scalars[2], a);
        atomicAdd(&scalars[1], b);
        atomicAdd(&scalars[3], c);
        atomicAdd(&scalars[4], d);
        __threadfence();
        float old = atomicAdd(&scalars[7], 1.0f);   // ticket
        if (old == (float)(N_MOLS / 256 - 1)) {
            float s0 = atomicAdd(&scalars[0], 0.0f);
            float s1 = atomicAdd(&scalars[1], 0.0f);
            float s2 = atomicAdd(&scalars[2], 0.0f);
            float s3 = atomicAdd(&scalars[3], 0.0f);
            float s4 = atomicAdd(&scalars[4], 0.0f);
            float relu_neg = s0 - s4;
            float p2mv  = s1 / (float)N_PROTS;
            float m2pv  = s2 / (float)N_MOLS;
            float rankv = s3 / ((float)N_PROTS * 28.0f);
            float negv  = relu_neg / ((float)N_PROTS * (float)N_MOLS);
            out[0] = p2mv + m2pv + 0.5f * rankv + 0.1f * negv;
            out[1] = p2mv;
            out[2] = m2pv;
            out[3] = rankv;
            out[4] = negv;
        }
    }
}

extern "C" void kernel_launch(void* const* d_in, const int* in_sizes, int n_in,
                              void* d_out, int out_size, void* d_ws, size_t ws_size,
                              hipStream_t stream) {
    const float* prot   = (const float*)d_in[0];
    const float* mol    = (const float*)d_in[1];
    const float* pic50  = (const float*)d_in[3];
    const float* lscale = (const float*)d_in[4];

    float* ws      = (float*)d_ws;
    float* row_se  = ws;
    float* col_se  = ws + 2048;
    float* pos_sim = ws + 2048 + 16384;
    float* scalars = ws + 34816;

    if (ws_size >= WS_NEED) {
        unsigned char* protF8 = (unsigned char*)((char*)d_ws + PROT_F8_OFF_B);
        unsigned char* molF8  = (unsigned char*)((char*)d_ws + MOL_F8_OFF_B);
        size_t groups = ((size_t)N_PROTS + N_MOLS) * DIM / 8;   // 1,769,472
        convert_fp8<<<(unsigned)(groups / 256), 256, 0, stream>>>(prot, mol, protF8, molF8, ws);
        sim_pass_fp8<<<512, 512, 0, stream>>>(protF8, molF8, lscale, row_se, col_se, pos_sim, scalars);
    } else {
        hipMemsetAsync(d_ws, 0, (size_t)ACC_FLOATS * sizeof(float), stream);
        dim3 grid(N_MOLS / 128, N_PROTS / 128);
        sim_pass<<<grid, 256, 0, stream>>>(prot, mol, lscale, row_se, col_se, pos_sim, scalars);
    }
    finalize_mb<<<N_MOLS / 256, 256, 0, stream>>>(row_se, col_se, pos_sim, pic50, scalars, (float*)d_out);
}